// Round 9
// baseline (58.702 us; speedup 1.0000x reference)
//
#include <hip/hip_runtime.h>
#include <hip/hip_bf16.h>

// Fused GNN layer: h = x + segment_mean(x[edge_src] by edge_dst); out = relu(h@W + b)
//
// Full path (ws >= ~26.5 MB):
//   prep_full: row_ptr scatter + W bf16 MFMA-fragment pack + x -> bf16 (xb)
//   main3: BR=32/block (3125 blocks), quarter-wave (16 lanes) owns TWO rows;
//          both rows' first 8-deep bf16 gather batches issued before any
//          consumption (16 loads/lane in flight). bf16 MFMA GEMM phase.
// Medium path (ws >= ~433 KB): round-7 kernels (fp32 gather, rp + pkW).
// Small path: self-contained kernel (binary search + inline W pack).

#define FD  128
#define BR  32     // rows per block (main3)
#define BRF 64     // rows per block (fallback kernels)
#define HSB 136    // LDS h row stride in bf16 elems

typedef __attribute__((ext_vector_type(8))) short bf16x8;
typedef __attribute__((ext_vector_type(4))) float f32x4;

__device__ __forceinline__ short f2bf(float f) {
    unsigned u = __float_as_uint(f);
    return (short)((u + 0x7FFFu + ((u >> 16) & 1u)) >> 16);   // RNE
}
__device__ __forceinline__ float bf2f(short s) {
    return __uint_as_float(((unsigned)(unsigned short)s) << 16);
}

// ---------------- prep (full): rp + packed W + x->bf16 ----------------
__global__ __launch_bounds__(256) void prep_full_kernel(
    const float* __restrict__ x, const float* __restrict__ W,
    const int* __restrict__ edst, int* __restrict__ rp,
    short* __restrict__ pkW, short* __restrict__ xb, int N, int E)
{
    const int gid = blockIdx.x * 256 + threadIdx.x;
    const int nth = gridDim.x * 256;

    const int nv = N * FD / 8;
    for (int i = gid; i < nv; i += nth) {
        float4 f0 = *(const float4*)(x + (size_t)i * 8);
        float4 f1 = *(const float4*)(x + (size_t)i * 8 + 4);
        short tmp[8] = {f2bf(f0.x), f2bf(f0.y), f2bf(f0.z), f2bf(f0.w),
                        f2bf(f1.x), f2bf(f1.y), f2bf(f1.z), f2bf(f1.w)};
        *(bf16x8*)(xb + (size_t)i * 8) = *(bf16x8*)tmp;
    }
    for (int e = gid; e < E; e += nth) {
        int cur = edst[e];
        int prev = e ? edst[e - 1] : -1;
        for (int v = prev + 1; v <= cur; ++v) rp[v] = e;
        if (e == E - 1)
            for (int v = cur + 1; v <= N; ++v) rp[v] = E;
    }
    if (E == 0) {  // safety: empty edge list
        for (int v = gid; v <= N; v += nth) rp[v] = 0;
    }
    if (gid < 2048) {
        int wave = gid >> 9, rem = gid & 511;
        int ct = rem >> 8, rem2 = rem & 255;
        int kt = rem2 >> 6, lane = rem2 & 63;
        int q = lane >> 4, lr = lane & 15;
        int col = wave * 32 + ct * 16 + lr;
        int k0 = kt * 32 + q * 8;
        short tmp[8];
#pragma unroll
        for (int e2 = 0; e2 < 8; ++e2)
            tmp[e2] = f2bf(W[(size_t)(k0 + e2) * FD + col]);
        *(bf16x8*)(pkW + (size_t)gid * 8) = *(bf16x8*)tmp;
    }
}

// ---------------- main3 helpers ----------------
__device__ __forceinline__ void issue8(const short* __restrict__ xb, int srcv,
                                       int qb, int ql, int j0, int m, uint4 v[8])
{
#pragma unroll
    for (int u = 0; u < 8; ++u) {
        int jj = j0 + u;
        int idx = __shfl(srcv, qb + (jj & 15));
        if (jj >= m) idx = 0;    // dummy -> hot row 0
        v[u] = *(const uint4*)(xb + (size_t)idx * FD + 8 * ql);
    }
}

__device__ __forceinline__ void acc8(const uint4 v[8], int c, float2 a[4])
{
#pragma unroll
    for (int u = 0; u < 8; ++u) {
        float f = (u < c) ? 1.f : 0.f;
        unsigned w;
        w = v[u].x;
        a[0].x = fmaf(__uint_as_float(w << 16), f, a[0].x);
        a[0].y = fmaf(__uint_as_float(w & 0xFFFF0000u), f, a[0].y);
        w = v[u].y;
        a[1].x = fmaf(__uint_as_float(w << 16), f, a[1].x);
        a[1].y = fmaf(__uint_as_float(w & 0xFFFF0000u), f, a[1].y);
        w = v[u].z;
        a[2].x = fmaf(__uint_as_float(w << 16), f, a[2].x);
        a[2].y = fmaf(__uint_as_float(w & 0xFFFF0000u), f, a[2].y);
        w = v[u].w;
        a[3].x = fmaf(__uint_as_float(w << 16), f, a[3].x);
        a[3].y = fmaf(__uint_as_float(w & 0xFFFF0000u), f, a[3].y);
    }
}

__device__ __forceinline__ void row_tail(const short* __restrict__ xb,
                                         const int* __restrict__ esrc,
                                         int s, int e, int srcv,
                                         int qb, int ql, float2 a[4])
{
    int deg = e - s;
    if (deg > 8) {
        uint4 v2[8];
        int m16 = deg < 16 ? deg : 16;
        issue8(xb, srcv, qb, ql, 8, m16, v2);
        acc8(v2, m16 - 8, a);
        for (int cs = s + 16; cs < e; cs += 16) {
            int m = e - cs; if (m > 16) m = 16;
            int sv = (cs + ql < e) ? esrc[cs + ql] : 0;
            for (int j0 = 0; j0 < m; j0 += 8) {
                issue8(xb, sv, qb, ql, j0, m, v2);
                int c = m - j0; if (c > 8) c = 8;
                acc8(v2, c, a);
            }
        }
    }
}

__device__ __forceinline__ void finalize_row(short* shb, int rb, int ql,
                                             const bf16x8 xv, const float2 a[4], int deg)
{
    float inv = 1.0f / (float)(deg > 0 ? deg : 1);
    short hb[8];
#pragma unroll
    for (int k = 0; k < 4; ++k) {
        hb[2 * k]     = f2bf(bf2f(xv[2 * k])     + a[k].x * inv);
        hb[2 * k + 1] = f2bf(bf2f(xv[2 * k + 1]) + a[k].y * inv);
    }
    *(bf16x8*)(shb + rb * HSB + 8 * ql) = *(bf16x8*)hb;
}

// ---------------- main3: BR=32, 2 rows per quarter-wave ----------------
__global__ __launch_bounds__(256) void meanagg_main3_kernel(
    const short* __restrict__ xb, const short* __restrict__ pkW,
    const float* __restrict__ bias, const int* __restrict__ esrc,
    const int* __restrict__ rp, float* __restrict__ out, int N, int E)
{
    __shared__ short shb[BR * HSB];
    __shared__ int seg[BR + 1];

    const int t = threadIdx.x;
    const int base = blockIdx.x * BR;

    if (t < BR + 1) {
        int idx = base + t;
        seg[t] = rp[idx > N ? N : idx];
    }
    __syncthreads();

    const int wave = t >> 6;
    const int lane = t & 63;
    const int qw = lane >> 4;      // quarter-wave id
    const int ql = lane & 15;      // sublane: owns features [8ql, 8ql+8)
    const int qb = qw << 4;        // shfl lane base

    const int rb0 = wave * 8 + qw; // first row of this quarter-wave
    const int rb1 = rb0 + 4;       // second row
    const int r0 = base + rb0, r1 = base + rb1;

    const int s0 = seg[rb0], e0 = seg[rb0 + 1];
    const int s1 = seg[rb1], e1 = seg[rb1 + 1];

    // index batches (one coalesced load each; covers first 16 edges/row)
    int srcv0 = (s0 + ql < e0) ? esrc[s0 + ql] : 0;
    int srcv1 = (s1 + ql < e1) ? esrc[s1 + ql] : 0;
    bf16x8 xv0 = {0, 0, 0, 0, 0, 0, 0, 0}, xv1 = xv0;
    if (r0 < N) xv0 = *(const bf16x8*)(xb + (size_t)r0 * FD + 8 * ql);
    if (r1 < N) xv1 = *(const bf16x8*)(xb + (size_t)r1 * FD + 8 * ql);

    const int deg0 = e0 - s0, deg1 = e1 - s1;
    const int m0 = deg0 < 16 ? deg0 : 16;
    const int m1 = deg1 < 16 ? deg1 : 16;

    // issue BOTH rows' first 8-deep gather batches before consuming anything
    uint4 v0[8], v1[8];
    issue8(xb, srcv0, qb, ql, 0, m0, v0);
    issue8(xb, srcv1, qb, ql, 0, m1, v1);

    float2 a[4] = {{0.f, 0.f}, {0.f, 0.f}, {0.f, 0.f}, {0.f, 0.f}};
    acc8(v0, m0 < 8 ? m0 : 8, a);
    row_tail(xb, esrc, s0, e0, srcv0, qb, ql, a);
    finalize_row(shb, rb0, ql, xv0, a, deg0);

    a[0] = a[1] = a[2] = a[3] = make_float2(0.f, 0.f);
    acc8(v1, m1 < 8 ? m1 : 8, a);
    row_tail(xb, esrc, s1, e1, srcv1, qb, ql, a);
    finalize_row(shb, rb1, ql, xv1, a, deg1);

    __syncthreads();

    // Phase 2: bf16 MFMA GEMM h[32][128] @ W[128][128] + b, ReLU
    const int lr = lane & 15;
    const int q  = lane >> 4;
    const int colb = wave * 32;

    bf16x8 bfr[2][4];
#pragma unroll
    for (int ct = 0; ct < 2; ++ct)
#pragma unroll
        for (int kt = 0; kt < 4; ++kt) {
            int f = ((wave * 2 + ct) * 4 + kt) * 64 + lane;
            bfr[ct][kt] = *(const bf16x8*)(pkW + (size_t)f * 8);
        }

    f32x4 acc[2][2];
#pragma unroll
    for (int rt = 0; rt < 2; ++rt) {
        acc[rt][0] = (f32x4){0.f, 0.f, 0.f, 0.f};
        acc[rt][1] = (f32x4){0.f, 0.f, 0.f, 0.f};
    }

#pragma unroll
    for (int rt = 0; rt < 2; ++rt)
#pragma unroll
        for (int kt = 0; kt < 4; ++kt) {
            bf16x8 av = *(const bf16x8*)(shb + (rt * 16 + lr) * HSB + kt * 32 + q * 8);
            acc[rt][0] = __builtin_amdgcn_mfma_f32_16x16x32_bf16(av, bfr[0][kt], acc[rt][0], 0, 0, 0);
            acc[rt][1] = __builtin_amdgcn_mfma_f32_16x16x32_bf16(av, bfr[1][kt], acc[rt][1], 0, 0, 0);
        }

    const float b0 = bias[colb + lr];
    const float b1 = bias[colb + 16 + lr];

#pragma unroll
    for (int rt = 0; rt < 2; ++rt)
#pragma unroll
        for (int j = 0; j < 4; ++j) {
            int row = base + rt * 16 + q * 4 + j;
            if (row < N) {
                float o0 = acc[rt][0][j] + b0; o0 = o0 > 0.f ? o0 : 0.f;
                float o1 = acc[rt][1][j] + b1; o1 = o1 > 0.f ? o1 : 0.f;
                out[(size_t)row * FD + colb + lr]      = o0;
                out[(size_t)row * FD + colb + 16 + lr] = o1;
            }
        }
}

// ---------------- medium path: rp + pkW, fp32 gather (round-7) ----------------
__global__ __launch_bounds__(256) void prep_kernel(
    const float* __restrict__ W, const int* __restrict__ edst,
    int* __restrict__ rp, short* __restrict__ pkW, int N, int E)
{
    int gid = blockIdx.x * 256 + threadIdx.x;
    if (gid < E) {
        int cur = edst[gid];
        int prev = gid ? edst[gid - 1] : -1;
        for (int v = prev + 1; v <= cur; ++v) rp[v] = gid;
        if (gid == E - 1)
            for (int v = cur + 1; v <= N; ++v) rp[v] = E;
    }
    if (gid < 2048) {
        int wave = gid >> 9, rem = gid & 511;
        int ct = rem >> 8, rem2 = rem & 255;
        int kt = rem2 >> 6, lane = rem2 & 63;
        int q = lane >> 4, lr = lane & 15;
        int col = wave * 32 + ct * 16 + lr;
        int k0 = kt * 32 + q * 8;
        short tmp[8];
#pragma unroll
        for (int e = 0; e < 8; ++e)
            tmp[e] = f2bf(W[(size_t)(k0 + e) * FD + col]);
        *(bf16x8*)(pkW + (size_t)gid * 8) = *(bf16x8*)tmp;
    }
}

__global__ __launch_bounds__(256) void meanagg_main_kernel(
    const float* __restrict__ x, const short* __restrict__ pkW,
    const float* __restrict__ bias, const int* __restrict__ esrc,
    const int* __restrict__ rp, float* __restrict__ out, int N, int E)
{
    __shared__ short shb[BRF * HSB];
    __shared__ int seg[BRF + 1];

    const int t = threadIdx.x;
    const int base = blockIdx.x * BRF;

    if (t < BRF + 1) {
        int idx = base + t;
        seg[t] = rp[idx > N ? N : idx];
    }
    __syncthreads();

    const int wave = t >> 6;
    const int lane = t & 63;
    const int sw = lane >> 5;
    const int sl = lane & 31;
    const int lb = sw << 5;
    const int rowbase = wave * 16;

    for (int it = 0; it < 8; ++it) {
        int cur_rb = rowbase + it * 2 + sw;
        int cur_r  = base + cur_rb;
        if (cur_r >= N) break;
        int cur_s = seg[cur_rb], cur_e = seg[cur_rb + 1];
        float4 a0 = make_float4(0.f, 0.f, 0.f, 0.f), a1 = a0;
        for (int cs = cur_s; cs < cur_e; cs += 32) {
            int m = cur_e - cs; if (m > 32) m = 32;
            int srcv = (cs + sl < cur_e) ? esrc[cs + sl] : 0;
            for (int j0 = 0; j0 < m; j0 += 8) {
                const int rem = m - j0;
#pragma unroll
                for (int u = 0; u < 8; ++u) {
                    int idx = __shfl(srcv, lb + ((j0 + u) & 31));
                    float4 v = *(const float4*)(x + (size_t)idx * FD + 4 * sl);
                    float f = (u < rem) ? 1.f : 0.f;
                    float4* A = (u & 1) ? &a1 : &a0;
                    A->x = fmaf(v.x, f, A->x);
                    A->y = fmaf(v.y, f, A->y);
                    A->z = fmaf(v.z, f, A->z);
                    A->w = fmaf(v.w, f, A->w);
                }
            }
        }
        float4 xv = *(const float4*)(x + (size_t)cur_r * FD + 4 * sl);
        int deg = cur_e - cur_s;
        float inv = 1.0f / (float)(deg > 0 ? deg : 1);
        short4 hb;
        hb.x = f2bf(xv.x + (a0.x + a1.x) * inv);
        hb.y = f2bf(xv.y + (a0.y + a1.y) * inv);
        hb.z = f2bf(xv.z + (a0.z + a1.z) * inv);
        hb.w = f2bf(xv.w + (a0.w + a1.w) * inv);
        *(short4*)(shb + cur_rb * HSB + 4 * sl) = hb;
    }
    __syncthreads();

    const int lr = lane & 15;
    const int q  = lane >> 4;
    const int colb = wave * 32;

    bf16x8 bfr[2][4];
#pragma unroll
    for (int ct = 0; ct < 2; ++ct)
#pragma unroll
        for (int kt = 0; kt < 4; ++kt) {
            int f = ((wave * 2 + ct) * 4 + kt) * 64 + lane;
            bfr[ct][kt] = *(const bf16x8*)(pkW + (size_t)f * 8);
        }

    f32x4 acc[4][2];
#pragma unroll
    for (int rt = 0; rt < 4; ++rt) {
        acc[rt][0] = (f32x4){0.f, 0.f, 0.f, 0.f};
        acc[rt][1] = (f32x4){0.f, 0.f, 0.f, 0.f};
    }

#pragma unroll
    for (int rt = 0; rt < 4; ++rt)
#pragma unroll
        for (int kt = 0; kt < 4; ++kt) {
            bf16x8 av = *(const bf16x8*)(shb + (rt * 16 + lr) * HSB + kt * 32 + q * 8);
            acc[rt][0] = __builtin_amdgcn_mfma_f32_16x16x32_bf16(av, bfr[0][kt], acc[rt][0], 0, 0, 0);
            acc[rt][1] = __builtin_amdgcn_mfma_f32_16x16x32_bf16(av, bfr[1][kt], acc[rt][1], 0, 0, 0);
        }

    const float b0 = bias[colb + lr];
    const float b1 = bias[colb + 16 + lr];

#pragma unroll
    for (int rt = 0; rt < 4; ++rt)
#pragma unroll
        for (int j = 0; j < 4; ++j) {
            int row = base + rt * 16 + q * 4 + j;
            if (row < N) {
                float v0 = acc[rt][0][j] + b0; v0 = v0 > 0.f ? v0 : 0.f;
                float v1 = acc[rt][1][j] + b1; v1 = v1 > 0.f ? v1 : 0.f;
                out[(size_t)row * FD + colb + lr]      = v0;
                out[(size_t)row * FD + colb + 16 + lr] = v1;
            }
        }
}

// ---------------- small path: self-contained ----------------
__global__ __launch_bounds__(256) void meanagg_fused_kernel(
    const float* __restrict__ x, const float* __restrict__ W,
    const float* __restrict__ bias, const int* __restrict__ esrc,
    const int* __restrict__ edst, float* __restrict__ out, int N, int E)
{
    __shared__ short shb[BRF * HSB];
    __shared__ int seg[BRF + 1];

    const int t = threadIdx.x;
    const int base = blockIdx.x * BRF;

    if (t < BRF + 1) {
        int v = base + t;
        int lo = 0, hi = E;
        while (lo < hi) {
            int mid = (lo + hi) >> 1;
            if (edst[mid] < v) lo = mid + 1; else hi = mid;
        }
        seg[t] = lo;
    }
    __syncthreads();

    const int wave = t >> 6;
    const int lane = t & 63;
    const int sw = lane >> 5;
    const int sl = lane & 31;
    const int lb = sw << 5;
    const int rowbase = wave * 16;

    for (int it = 0; it < 8; ++it) {
        int cur_rb = rowbase + it * 2 + sw;
        int cur_r  = base + cur_rb;
        if (cur_r >= N) break;
        int cur_s = seg[cur_rb], cur_e = seg[cur_rb + 1];
        float4 a0 = make_float4(0.f, 0.f, 0.f, 0.f), a1 = a0;
        for (int cs = cur_s; cs < cur_e; cs += 32) {
            int m = cur_e - cs; if (m > 32) m = 32;
            int srcv = (cs + sl < cur_e) ? esrc[cs + sl] : 0;
            for (int j0 = 0; j0 < m; j0 += 8) {
                const int rem = m - j0;
#pragma unroll
                for (int u = 0; u < 8; ++u) {
                    int idx = __shfl(srcv, lb + ((j0 + u) & 31));
                    float4 v = *(const float4*)(x + (size_t)idx * FD + 4 * sl);
                    float f = (u < rem) ? 1.f : 0.f;
                    float4* A = (u & 1) ? &a1 : &a0;
                    A->x = fmaf(v.x, f, A->x);
                    A->y = fmaf(v.y, f, A->y);
                    A->z = fmaf(v.z, f, A->z);
                    A->w = fmaf(v.w, f, A->w);
                }
            }
        }
        float4 xv = *(const float4*)(x + (size_t)cur_r * FD + 4 * sl);
        int deg = cur_e - cur_s;
        float inv = 1.0f / (float)(deg > 0 ? deg : 1);
        short4 hb;
        hb.x = f2bf(xv.x + (a0.x + a1.x) * inv);
        hb.y = f2bf(xv.y + (a0.y + a1.y) * inv);
        hb.z = f2bf(xv.z + (a0.z + a1.z) * inv);
        hb.w = f2bf(xv.w + (a0.w + a1.w) * inv);
        *(short4*)(shb + cur_rb * HSB + 4 * sl) = hb;
    }
    __syncthreads();

    const int lr = lane & 15;
    const int q  = lane >> 4;
    const int colb = wave * 32;

    bf16x8 bfr[2][4];
#pragma unroll
    for (int ct = 0; ct < 2; ++ct) {
        int col = colb + ct * 16 + lr;
#pragma unroll
        for (int kt = 0; kt < 4; ++kt) {
            bf16x8 f;
#pragma unroll
            for (int e = 0; e < 8; ++e)
                f[e] = f2bf(W[(size_t)(kt * 32 + q * 8 + e) * FD + col]);
            bfr[ct][kt] = f;
        }
    }

    f32x4 acc[4][2];
#pragma unroll
    for (int rt = 0; rt < 4; ++rt) {
        acc[rt][0] = (f32x4){0.f, 0.f, 0.f, 0.f};
        acc[rt][1] = (f32x4){0.f, 0.f, 0.f, 0.f};
    }

#pragma unroll
    for (int rt = 0; rt < 4; ++rt)
#pragma unroll
        for (int kt = 0; kt < 4; ++kt) {
            bf16x8 av = *(const bf16x8*)(shb + (rt * 16 + lr) * HSB + kt * 32 + q * 8);
            acc[rt][0] = __builtin_amdgcn_mfma_f32_16x16x32_bf16(av, bfr[0][kt], acc[rt][0], 0, 0, 0);
            acc[rt][1] = __builtin_amdgcn_mfma_f32_16x16x32_bf16(av, bfr[1][kt], acc[rt][1], 0, 0, 0);
        }

    const float b0 = bias[colb + lr];
    const float b1 = bias[colb + 16 + lr];

#pragma unroll
    for (int rt = 0; rt < 4; ++rt)
#pragma unroll
        for (int j = 0; j < 4; ++j) {
            int row = base + rt * 16 + q * 4 + j;
            if (row < N) {
                float v0 = acc[rt][0][j] + b0; v0 = v0 > 0.f ? v0 : 0.f;
                float v1 = acc[rt][1][j] + b1; v1 = v1 > 0.f ? v1 : 0.f;
                out[(size_t)row * FD + colb + lr]      = v0;
                out[(size_t)row * FD + colb + 16 + lr] = v1;
            }
        }
}

extern "C" void kernel_launch(void* const* d_in, const int* in_sizes, int n_in,
                              void* d_out, int out_size, void* d_ws, size_t ws_size,
                              hipStream_t stream) {
    const float* x    = (const float*)d_in[0];
    const float* W    = (const float*)d_in[1];
    const float* bias = (const float*)d_in[2];
    const int* esrc   = (const int*)d_in[3];
    const int* edst   = (const int*)d_in[4];
    float* out        = (float*)d_out;

    int N = in_sizes[0] / FD;
    int E = in_sizes[3];

    size_t rp_bytes = (size_t)(N + 1) * 4;
    size_t pk_off   = (rp_bytes + 511) & ~(size_t)511;
    size_t xb_off   = (pk_off + 2048 * 8 * 2 + 511) & ~(size_t)511;
    size_t need_med = pk_off + 2048 * 8 * 2;
    size_t need_big = xb_off + (size_t)N * FD * 2;

    if (ws_size >= need_big) {
        int* rp    = (int*)d_ws;
        short* pkW = (short*)((char*)d_ws + pk_off);
        short* xb  = (short*)((char*)d_ws + xb_off);
        int blocks = (N + BR - 1) / BR;
        prep_full_kernel<<<2048, 256, 0, stream>>>(x, W, edst, rp, pkW, xb, N, E);
        meanagg_main3_kernel<<<blocks, 256, 0, stream>>>(xb, pkW, bias, esrc, rp, out, N, E);
    } else if (ws_size >= need_med) {
        int* rp    = (int*)d_ws;
        short* pkW = (short*)((char*)d_ws + pk_off);
        int blocks = (N + BRF - 1) / BRF;
        int pblocks = (E + 255) / 256;
        prep_kernel<<<pblocks, 256, 0, stream>>>(W, edst, rp, pkW, N, E);
        meanagg_main_kernel<<<blocks, 256, 0, stream>>>(x, pkW, bias, esrc, rp, out, N, E);
    } else {
        int blocks = (N + BRF - 1) / BRF;
        meanagg_fused_kernel<<<blocks, 256, 0, stream>>>(x, W, bias, esrc, edst, out, N, E);
    }
}